// Round 2
// baseline (187.078 us; speedup 1.0000x reference)
//
#include <hip/hip_runtime.h>
#include <hip/hip_bf16.h>
#include <stdint.h>

#define FEATURES 256
#define SYMBOLS  1024
#define NPIX     65536        // 16*64*64
#define M_TILE   128
#define THREADS  256
#define SMEM_BYTES 65536      // A-stage region (64 KB); B double-buffers overlay it

typedef float  f32x4  __attribute__((ext_vector_type(4)));
typedef __bf16 bf16x4 __attribute__((ext_vector_type(4)));
typedef __bf16 bf16x8 __attribute__((ext_vector_type(8)));

// async global->LDS DMA, 16 B per lane; LDS dest = uniform base + lane*16
__device__ __forceinline__ void gld_lds16(const void* g, void* l) {
    __builtin_amdgcn_global_load_lds(
        (const __attribute__((address_space(1))) unsigned int*)g,
        (__attribute__((address_space(3))) unsigned int*)l, 16, 0, 0);
}

// ---- prep: W fp32 -> bf16 (ws), wnorm = ||w_s||^2 (ws), zero deviation slot ----
__global__ __launch_bounds__(64) void vq_prep(const float* __restrict__ W,
                                              __bf16* __restrict__ Wb,
                                              float* __restrict__ wnorm,
                                              float* __restrict__ devslot) {
    int s = blockIdx.x;
    int lane = threadIdx.x;
    f32x4 v = ((const f32x4*)(W + (size_t)s * FEATURES))[lane];
    float ss = v[0]*v[0] + v[1]*v[1] + v[2]*v[2] + v[3]*v[3];
    bf16x4 b;
    b[0] = (__bf16)v[0]; b[1] = (__bf16)v[1]; b[2] = (__bf16)v[2]; b[3] = (__bf16)v[3];
    *(bf16x4*)(Wb + (size_t)s * FEATURES + lane * 4) = b;
    #pragma unroll
    for (int off = 32; off > 0; off >>= 1) ss += __shfl_xor(ss, off);
    if (lane == 0) wnorm[s] = ss;
    if (s == 0 && lane == 0) *devslot = 0.f;
}

// ---- main: A-stationary fused GEMM-argmin + gather-out + deviation ----
__global__ __launch_bounds__(THREADS, 2) void vq_main(
        const float*  __restrict__ x,
        const float*  __restrict__ W,
        const __bf16* __restrict__ Wb,
        const float*  __restrict__ wnorm,
        float*        __restrict__ out,
        float*        __restrict__ devslot) {
    extern __shared__ char smem[];
    const int t    = threadIdx.x;
    const int lane = t & 63;
    const int wave = t >> 6;
    const int quad = lane >> 4;
    const int l16  = lane & 15;
    const int wm   = wave >> 1;          // 2x2 wave grid over the 128x128 C tile
    const int wn   = wave & 1;
    const int m0   = blockIdx.x * M_TILE;
    const float scale = 1.25f / (float)((size_t)NPIX * FEATURES);

    // ---- Stage A: x[128][256] fp32 -> bf16 into swizzled LDS; accumulate ||x||^2 ----
    const f32x4* xblk = (const f32x4*)(x + (size_t)m0 * FEATURES);
    float ss = 0.f;
    #pragma unroll 8
    for (int i = 0; i < 32; ++i) {
        int f   = t + i * THREADS;
        int row = f >> 6;                // wave-uniform
        int k4  = f & 63;
        f32x4 v = xblk[f];
        ss += v[0]*v[0] + v[1]*v[1] + v[2]*v[2] + v[3]*v[3];
        bf16x4 b;
        b[0] = (__bf16)v[0]; b[1] = (__bf16)v[1]; b[2] = (__bf16)v[2]; b[3] = (__bf16)v[3];
        int kb   = k4 >> 1;              // 16B block within row (0..31)
        int phys = kb ^ (row & 7);       // XOR swizzle -> 2-way banks (free)
        *(bf16x4*)(smem + row * 512 + phys * 16 + (k4 & 1) * 8) = b;
    }
    #pragma unroll
    for (int off = 32; off > 0; off >>= 1) ss += __shfl_xor(ss, off);
    if (lane == 0) atomicAdd(devslot, scale * ss);
    __syncthreads();

    // ---- A fragments -> registers, once: af[mi][k8], k8 = K-slice of 32 ----
    bf16x8 af[4][8];
    #pragma unroll
    for (int mi = 0; mi < 4; ++mi) {
        int row = wm * 64 + mi * 16 + l16;
        #pragma unroll
        for (int k8 = 0; k8 < 8; ++k8) {
            int kb = k8 * 4 + quad;      // 0..31
            af[mi][k8] = *(const bf16x8*)(smem + row * 512 + ((kb ^ (row & 7)) * 16));
        }
    }
    __syncthreads();                     // A region dead; B buffers overlay it

    char* const bs0 = smem;              // 16 KB buffer 0
    char* const bs1 = smem + 16384;      // 16 KB buffer 1

    // prefetch tile tt2 = (nc<<2)|ktB : 128 symbols x 64 feats, swizzled via global addr
    const int n_off = lane >> 3;         // 0..7
    const int kbl   = lane & 7;
    auto prefetch = [&](int tt2) {
        int ncB = tt2 >> 2, ktB2 = tt2 & 3;
        char* buf = (tt2 & 1) ? bs1 : bs0;
        #pragma unroll
        for (int j = 0; j < 4; ++j) {
            int i = wave * 4 + j;        // instr 0..15, covers rows i*8..i*8+7
            int n = i * 8 + n_off;
            int kb = kbl ^ n_off;        // swizzled source block within the row
            const char* g = (const char*)Wb +
                ((size_t)(ncB * 128 + n) * 512 + (size_t)ktB2 * 128 + kb * 16);
            gld_lds16(g, buf + i * 1024);
        }
    };

    uint32_t best[16];
    #pragma unroll
    for (int j = 0; j < 16; ++j) best[j] = 0xFFFFFFFFu;

    prefetch(0);

    #pragma unroll 1
    for (int nc = 0; nc < 8; ++nc) {
        f32x4 acc[4][4] = {};
        #pragma unroll
        for (int ktB = 0; ktB < 4; ++ktB) {
            const int tt = nc * 4 + ktB;
            __syncthreads();             // drains vmcnt: buf[tt&1] ready
            if (ktB < 3 || nc < 7) prefetch(tt + 1);   // flies under the MFMAs below
            char* buf = (ktB & 1) ? bs1 : bs0;
            #pragma unroll
            for (int ks = 0; ks < 2; ++ks) {
                const int k8 = ktB * 2 + ks;
                bf16x8 bfr[4];
                #pragma unroll
                for (int ni = 0; ni < 4; ++ni) {
                    int n  = wn * 64 + ni * 16 + l16;
                    int kb = ks * 4 + quad;            // 0..7
                    bfr[ni] = *(const bf16x8*)(buf + n * 128 + ((kb ^ (n & 7)) * 16));
                }
                #pragma unroll
                for (int mi = 0; mi < 4; ++mi)
                    #pragma unroll
                    for (int ni = 0; ni < 4; ++ni)
                        acc[mi][ni] = __builtin_amdgcn_mfma_f32_16x16x32_bf16(
                            af[mi][k8], bfr[ni], acc[mi][ni], 0, 0, 0);
            }
        }
        // chunk epilogue: pack (quantized val | idx) and umin -> single-reg argmin
        #pragma unroll
        for (int ni = 0; ni < 4; ++ni) {
            int n = nc * 128 + wn * 64 + ni * 16 + l16;
            float wnv = wnorm[n];
            #pragma unroll
            for (int mi = 0; mi < 4; ++mi)
                #pragma unroll
                for (int r = 0; r < 4; ++r) {
                    float v2 = __builtin_fmaf(-2.f, acc[mi][ni][r], wnv);
                    uint32_t u = __float_as_uint(v2);
                    u ^= (u & 0x80000000u) ? 0xFFFFFFFFu : 0x80000000u;  // monotone map
                    uint32_t key = (u & 0xFFFFFC00u) | (uint32_t)n;      // ties -> low idx
                    int j = mi * 4 + r;
                    if (key < best[j]) best[j] = key;
                }
        }
    }

    // cross-lane merge: min over the 16 cols held by lanes of each quad
    #pragma unroll
    for (int j = 0; j < 16; ++j) {
        uint32_t v = best[j];
        #pragma unroll
        for (int off = 1; off < 16; off <<= 1) {
            uint32_t ov = (uint32_t)__shfl_xor((int)v, off);
            if (ov < v) v = ov;
        }
        best[j] = v;
    }

    __syncthreads();                     // done with B buffers; alias merge arrays
    uint32_t* mslot = (uint32_t*)smem;   // [2][128]
    int*      codes = (int*)(smem + 1024);

    if (l16 == 0) {                      // quad-uniform data, one writer per quad
        #pragma unroll
        for (int j = 0; j < 16; ++j) {
            int mi = j >> 2, r = j & 3;
            int row = wm * 64 + mi * 16 + quad * 4 + r;
            mslot[wn * 128 + row] = best[j];
        }
    }
    __syncthreads();

    if (t < 128) {                       // merge wn halves; deviation partial
        uint32_t s0 = mslot[t], s1 = mslot[128 + t];
        uint32_t s = (s1 < s0) ? s1 : s0;
        codes[t] = (int)(s & 1023u);
        uint32_t u = s & 0xFFFFFC00u;
        u = (u & 0x80000000u) ? (u & 0x7FFFFFFFu) : ~u;  // unmap monotone key
        float bv = __uint_as_float(u);   // = wnorm[code] - 2*best_dot (quantized)
        #pragma unroll
        for (int off = 32; off > 0; off >>= 1) bv += __shfl_xor(bv, off);
        if (lane == 0) atomicAdd(devslot, scale * bv);
    }
    __syncthreads();

    // ---- out = W[code] (exact fp32 gather from the original codebook) ----
    f32x4* oblk = (f32x4*)(out + (size_t)m0 * FEATURES);
    #pragma unroll 8
    for (int i = 0; i < 32; ++i) {
        int f    = t + i * THREADS;
        int row  = f >> 6;               // wave-uniform
        int k4   = f & 63;
        int code = codes[row];
        oblk[f] = ((const f32x4*)(W + (size_t)code * FEATURES))[k4];
    }
}

extern "C" void kernel_launch(void* const* d_in, const int* in_sizes, int n_in,
                              void* d_out, int out_size, void* d_ws, size_t ws_size,
                              hipStream_t stream) {
    const float* x = (const float*)d_in[0];
    const float* W = (const float*)d_in[1];
    float* out = (float*)d_out;

    __bf16* Wb    = (__bf16*)d_ws;                                          // 512 KB
    float*  wnorm = (float*)((char*)d_ws + (size_t)SYMBOLS * FEATURES * 2); // 4 KB
    float*  devslot = out + (size_t)NPIX * FEATURES;                        // d_out tail

    hipFuncSetAttribute(reinterpret_cast<const void*>(vq_main),
                        hipFuncAttributeMaxDynamicSharedMemorySize, SMEM_BYTES);

    vq_prep<<<SYMBOLS, 64, 0, stream>>>(W, Wb, wnorm, devslot);
    vq_main<<<NPIX / M_TILE, THREADS, SMEM_BYTES, stream>>>(x, W, Wb, wnorm, out, devslot);
}

// Round 3
// 175.744 us; speedup vs baseline: 1.0645x; 1.0645x over previous
//
#include <hip/hip_runtime.h>
#include <hip/hip_bf16.h>
#include <stdint.h>

#define FEATURES 256
#define SYMBOLS  1024
#define NPIX     65536        // 16*64*64
#define M_TILE   128
#define THREADS  256
#define SMEM_BYTES 65536      // A-stage region (64 KB); two 32 KB B buffers overlay it
#define TILE_BYTES 32768      // B tile: 128 symbols x 128 feats bf16, pre-swizzled

typedef float  f32x4  __attribute__((ext_vector_type(4)));
typedef __bf16 bf16x4 __attribute__((ext_vector_type(4)));
typedef __bf16 bf16x8 __attribute__((ext_vector_type(8)));

// async global->LDS DMA, 16 B per lane; LDS dest = uniform base + lane*16
__device__ __forceinline__ void gld_lds16(const void* g, void* l) {
    __builtin_amdgcn_global_load_lds(
        (const __attribute__((address_space(1))) unsigned int*)g,
        (__attribute__((address_space(3))) unsigned int*)l, 16, 0, 0);
}

// ---- prep: build DMA-image codebook tiles + wnorm + zero deviation slot ----
// Tile tt = nc*2 + kt holds symbols [nc*128, nc*128+128) x feats [kt*128, kt*128+128).
// Within a tile: row n is 256 B = 16 x 16B blocks; stored block p holds source
// feats kt*128 + (p ^ (n&15))*8 .. +8  (bank swizzle baked in -> 2-way conflicts).
__global__ __launch_bounds__(64) void vq_prep(const float* __restrict__ W,
                                              __bf16* __restrict__ Wt,
                                              float* __restrict__ wnorm,
                                              float* __restrict__ devslot) {
    int s = blockIdx.x;
    int lane = threadIdx.x;
    int n  = s & 127;
    int nc = s >> 7;
    // wnorm: 64 lanes x 4 floats
    f32x4 v = ((const f32x4*)(W + (size_t)s * FEATURES))[lane];
    float ss = v[0]*v[0] + v[1]*v[1] + v[2]*v[2] + v[3]*v[3];
    #pragma unroll
    for (int off = 32; off > 0; off >>= 1) ss += __shfl_xor(ss, off);
    if (lane == 0) wnorm[s] = ss;
    if (s == 0 && lane == 0) *devslot = 0.f;
    // tile image: lanes 0..31 each write one 16B block
    if (lane < 32) {
        int kt = lane >> 4;
        int p  = lane & 15;
        int kb = p ^ (n & 15);
        const float* src = W + (size_t)s * FEATURES + kt * 128 + kb * 8;
        bf16x8 b;
        #pragma unroll
        for (int j = 0; j < 8; ++j) b[j] = (__bf16)src[j];
        *(bf16x8*)((char*)Wt + (size_t)(nc * 2 + kt) * TILE_BYTES + n * 256 + p * 16) = b;
    }
}

// ---- main: A-stationary fused GEMM-argmin + gather-out + deviation ----
__global__ __launch_bounds__(THREADS)
__attribute__((amdgpu_waves_per_eu(2, 2)))        // cap 2 waves/SIMD -> 256 regs, no spill
void vq_main(
        const float*  __restrict__ x,
        const float*  __restrict__ W,
        const __bf16* __restrict__ Wt,
        const float*  __restrict__ wnorm,
        float*        __restrict__ out,
        float*        __restrict__ devslot) {
    extern __shared__ char smem[];
    const int t    = threadIdx.x;
    const int lane = t & 63;
    const int wave = t >> 6;
    const int quad = lane >> 4;
    const int l16  = lane & 15;
    const int wm   = wave >> 1;          // 2x2 wave grid over the 128x128 C tile
    const int wn   = wave & 1;
    const int m0   = blockIdx.x * M_TILE;
    const float scale = 1.25f / (float)((size_t)NPIX * FEATURES);

    // ---- Stage A: x[128][256] fp32 -> bf16 into swizzled LDS; accumulate ||x||^2 ----
    const f32x4* xblk = (const f32x4*)(x + (size_t)m0 * FEATURES);
    float ss = 0.f;
    #pragma unroll 8
    for (int i = 0; i < 32; ++i) {
        int f   = t + i * THREADS;
        int row = f >> 6;                // wave-uniform
        int k4  = f & 63;
        f32x4 v = xblk[f];
        ss += v[0]*v[0] + v[1]*v[1] + v[2]*v[2] + v[3]*v[3];
        bf16x4 b;
        b[0] = (__bf16)v[0]; b[1] = (__bf16)v[1]; b[2] = (__bf16)v[2]; b[3] = (__bf16)v[3];
        int kb   = k4 >> 1;              // 16B block within row (0..31)
        int phys = kb ^ (row & 7);       // XOR swizzle -> 2-way banks (free)
        *(bf16x4*)(smem + row * 512 + phys * 16 + (k4 & 1) * 8) = b;
    }
    #pragma unroll
    for (int off = 32; off > 0; off >>= 1) ss += __shfl_xor(ss, off);
    if (lane == 0) atomicAdd(devslot, scale * ss);
    __syncthreads();

    // ---- A fragments -> registers, once: af[mi][k8], k8 = K-slice of 32 ----
    bf16x8 af[4][8];
    #pragma unroll
    for (int mi = 0; mi < 4; ++mi) {
        int row = wm * 64 + mi * 16 + l16;
        #pragma unroll
        for (int k8 = 0; k8 < 8; ++k8) {
            int kb = k8 * 4 + quad;      // 0..31
            af[mi][k8] = *(const bf16x8*)(smem + row * 512 + ((kb ^ (row & 7)) * 16));
        }
    }
    __syncthreads();                     // A region dead; B buffers overlay it

    char* const bs0 = smem;              // 32 KB buffer 0
    char* const bs1 = smem + TILE_BYTES; // 32 KB buffer 1

    // lane-linear DMA: tile tt is a contiguous 32 KB image in Wt
    auto prefetch = [&](int tt) {
        char* buf = (tt & 1) ? bs1 : bs0;
        const char* g = (const char*)Wt + (size_t)tt * TILE_BYTES;
        #pragma unroll
        for (int j = 0; j < 8; ++j) {
            int i = wave * 8 + j;        // 32 instrs x 1 KB = 32 KB
            gld_lds16(g + i * 1024 + lane * 16, buf + i * 1024);
        }
    };

    uint32_t best[16];
    #pragma unroll
    for (int j = 0; j < 16; ++j) best[j] = 0xFFFFFFFFu;

    prefetch(0);

    #pragma unroll 1
    for (int nc = 0; nc < 8; ++nc) {
        f32x4 acc[4][4] = {};
        #pragma unroll
        for (int kt = 0; kt < 2; ++kt) {
            const int tt = nc * 2 + kt;
            __syncthreads();             // drains vmcnt: buf[tt&1] ready
            if (tt < 15) prefetch(tt + 1);   // flies under the MFMAs below
            char* buf = (tt & 1) ? bs1 : bs0;
            #pragma unroll
            for (int ks = 0; ks < 4; ++ks) {
                const int k8 = kt * 4 + ks;
                bf16x8 bfr[4];
                #pragma unroll
                for (int ni = 0; ni < 4; ++ni) {
                    int n    = wn * 64 + ni * 16 + l16;   // tile-local row
                    int kb   = ks * 4 + quad;             // 0..15
                    int phys = kb ^ (n & 15);
                    bfr[ni] = *(const bf16x8*)(buf + n * 256 + phys * 16);
                }
                #pragma unroll
                for (int mi = 0; mi < 4; ++mi)
                    #pragma unroll
                    for (int ni = 0; ni < 4; ++ni)
                        acc[mi][ni] = __builtin_amdgcn_mfma_f32_16x16x32_bf16(
                            af[mi][k8], bfr[ni], acc[mi][ni], 0, 0, 0);
            }
        }
        // chunk epilogue: pack (quantized val | idx) and umin -> single-reg argmin
        #pragma unroll
        for (int ni = 0; ni < 4; ++ni) {
            int n = nc * 128 + wn * 64 + ni * 16 + l16;
            float wnv = wnorm[n];
            #pragma unroll
            for (int mi = 0; mi < 4; ++mi)
                #pragma unroll
                for (int r = 0; r < 4; ++r) {
                    float v2 = __builtin_fmaf(-2.f, acc[mi][ni][r], wnv);
                    uint32_t u = __float_as_uint(v2);
                    u ^= (u & 0x80000000u) ? 0xFFFFFFFFu : 0x80000000u;  // monotone map
                    uint32_t key = (u & 0xFFFFFC00u) | (uint32_t)n;      // ties -> low idx
                    int j = mi * 4 + r;
                    if (key < best[j]) best[j] = key;
                }
        }
    }

    // cross-lane merge: min over the 16 cols held by lanes of each quad
    #pragma unroll
    for (int j = 0; j < 16; ++j) {
        uint32_t v = best[j];
        #pragma unroll
        for (int off = 1; off < 16; off <<= 1) {
            uint32_t ov = (uint32_t)__shfl_xor((int)v, off);
            if (ov < v) v = ov;
        }
        best[j] = v;
    }

    __syncthreads();                     // done with B buffers; alias merge arrays
    uint32_t* mslot = (uint32_t*)smem;   // [2][128]
    int*      codes = (int*)(smem + 1024);

    if (l16 == 0) {                      // quad-uniform data, one writer per quad
        #pragma unroll
        for (int j = 0; j < 16; ++j) {
            int mi = j >> 2, r = j & 3;
            int row = wm * 64 + mi * 16 + quad * 4 + r;
            mslot[wn * 128 + row] = best[j];
        }
    }
    __syncthreads();

    if (t < 128) {                       // merge wn halves; deviation partial
        uint32_t s0 = mslot[t], s1 = mslot[128 + t];
        uint32_t s = (s1 < s0) ? s1 : s0;
        codes[t] = (int)(s & 1023u);
        uint32_t u = s & 0xFFFFFC00u;
        u = (u & 0x80000000u) ? (u & 0x7FFFFFFFu) : ~u;  // unmap monotone key
        float bv = __uint_as_float(u);   // = wnorm[code] - 2*best_dot (quantized)
        #pragma unroll
        for (int off = 32; off > 0; off >>= 1) bv += __shfl_xor(bv, off);
        if (lane == 0) atomicAdd(devslot, scale * bv);
    }
    __syncthreads();

    // ---- out = W[code] (exact fp32 gather from the original codebook) ----
    f32x4* oblk = (f32x4*)(out + (size_t)m0 * FEATURES);
    #pragma unroll 8
    for (int i = 0; i < 32; ++i) {
        int f    = t + i * THREADS;
        int row  = f >> 6;               // wave-uniform
        int k4   = f & 63;
        int code = codes[row];
        oblk[f] = ((const f32x4*)(W + (size_t)code * FEATURES))[k4];
    }
}

extern "C" void kernel_launch(void* const* d_in, const int* in_sizes, int n_in,
                              void* d_out, int out_size, void* d_ws, size_t ws_size,
                              hipStream_t stream) {
    const float* x = (const float*)d_in[0];
    const float* W = (const float*)d_in[1];
    float* out = (float*)d_out;

    __bf16* Wt    = (__bf16*)d_ws;                                          // 512 KB tiled
    float*  wnorm = (float*)((char*)d_ws + (size_t)SYMBOLS * FEATURES * 2); // 4 KB
    float*  devslot = out + (size_t)NPIX * FEATURES;                        // d_out tail

    hipFuncSetAttribute(reinterpret_cast<const void*>(vq_main),
                        hipFuncAttributeMaxDynamicSharedMemorySize, SMEM_BYTES);

    vq_prep<<<SYMBOLS, 64, 0, stream>>>(W, Wt, wnorm, devslot);
    vq_main<<<NPIX / M_TILE, THREADS, SMEM_BYTES, stream>>>(x, W, Wt, wnorm, out, devslot);
}